// Round 5
// baseline (655.796 us; speedup 1.0000x reference)
//
#include <hip/hip_runtime.h>
#include <hip/hip_bf16.h>
#include <math.h>

#define BDIM   8
#define TDIM   2048
#define DDIM   512
#define PDIM   8
#define NTOK   (BDIM * TDIM)        // 16384
#define KDIM   (DDIM * PDIM)        // 4096
#define EPSF   1e-6f

typedef __attribute__((ext_vector_type(16))) float floatx16;
typedef __attribute__((ext_vector_type(8))) _Float16 half8;
typedef __attribute__((ext_vector_type(2))) _Float16 half2v;

// ================= prep (all 5 APL layers, hoisted) =================
// prmh[layer][i*16 + 0..7]  = fp16 inv for p=0..7   (p=0: 0)
// prmh[layer][i*16 + 8..15] = fp16 ofs for p=0..7   (p=0: 1)
// also zeroes bias (prep_bias accumulates with atomics afterwards)
__global__ void prep_prmh_kernel(const float* p0, const float* p1,
                                 const float* p2, const float* p3,
                                 const float* p4,
                                 unsigned short* __restrict__ prmh,
                                 float* __restrict__ bias_all) {
    int layer = blockIdx.x;
    int i = threadIdx.x;  // 0..511
    bias_all[layer * DDIM + i] = 0.f;
    const float* pts = layer == 0 ? p0 : layer == 1 ? p1 : layer == 2 ? p2
                     : layer == 3 ? p3 : p4;
    unsigned short* dst = prmh + (size_t)layer * DDIM * 16 + (size_t)i * 16;
    _Float16 invh[8], ofsh[8];
    invh[0] = (_Float16)0.f; ofsh[0] = (_Float16)1.f;
    #pragma unroll
    for (int p = 1; p < 8; ++p) {
        float a = pts[i * 8 + p - 1];
        float b = pts[i * 8 + p];
        float inv = 1.0f / (b - a);
        invh[p] = (_Float16)inv;
        ofsh[p] = (_Float16)(-a * inv);
    }
    *(uint4*)(dst)     = *(const uint4*)invh;
    *(uint4*)(dst + 8) = *(const uint4*)ofsh;
}

// W -> fp16, first-differenced, k-octet-interleaved; p=0 col zeroed (bias)
__global__ void prep_wtt_kernel(const float* v0, const float* v1,
                                const float* v2, const float* v3,
                                const float* v4,
                                unsigned short* __restrict__ Wtt_all) {
    int layer = blockIdx.y;
    const float* v = layer == 0 ? v0 : layer == 1 ? v1 : layer == 2 ? v2
                   : layer == 3 ? v3 : v4;
    unsigned short* Wtt = Wtt_all + (size_t)layer * KDIM * DDIM;
    int idx = blockIdx.x * blockDim.x + threadIdx.x;   // oct*512 + o
    int oct = idx >> 9, o = idx & 511;
    unsigned short f8[8];
    float prev = v[(size_t)(oct * 8) * DDIM + o];
    f8[0] = 0;
    #pragma unroll
    for (int p = 1; p < 8; ++p) {
        float cur = v[(size_t)(oct * 8 + p) * DDIM + o];
        float d = cur - prev;
        prev = cur;
        _Float16 hv = (_Float16)d;
        f8[p] = *reinterpret_cast<unsigned short*>(&hv);
    }
    *(uint4*)&Wtt[(size_t)idx * 8] = *(const uint4*)f8;
}

// bias[layer][o] += partial sums of v[i][0][o]  (coalesced, atomic combine)
__global__ void prep_bias_kernel(const float* v0, const float* v1,
                                 const float* v2, const float* v3,
                                 const float* v4,
                                 float* __restrict__ bias_all) {
    int layer = blockIdx.y;
    const float* v = layer == 0 ? v0 : layer == 1 ? v1 : layer == 2 ? v2
                   : layer == 3 ? v3 : v4;
    int o = threadIdx.x;               // 0..511
    int ig = blockIdx.x;               // 32 groups of 16 i's
    float s = 0.f;
    #pragma unroll
    for (int r = 0; r < 16; ++r) {
        int i = ig * 16 + r;
        s += v[(size_t)i * PDIM * DDIM + o];
    }
    atomicAdd(&bias_all[layer * DDIM + o], s);
}

// ================= fused ramp-feature MFMA GEMM (32x32x16 f16) ==========
// 1D grid, XCD-aware decode: n-block = xcd*16 + (j&15) so each XCD's
// resident blocks share a 4 MB act slice (L2-sized). blockIdx.x encodes
// (xcd, n, o, zi); zi selects the z-gate vs h_bar param set.
__launch_bounds__(256, 4)
__global__ void apl_gemm_mfma(const float* __restrict__ act,       // (N, D)
                              const unsigned short* __restrict__ WttA,
                              const unsigned short* __restrict__ WttB,
                              const unsigned short* __restrict__ prmA,
                              const unsigned short* __restrict__ prmB,
                              const float* __restrict__ biasA,
                              const float* __restrict__ biasB,
                              float* __restrict__ outA,
                              float* __restrict__ outB,
                              int sigA, int sigB) {
    __shared__ unsigned short As[128 * 40];      // [n][k], stride 40
    __shared__ unsigned short Bs[4 * 128 * 8];   // [k-octet][o][p]

    const int flat = blockIdx.x;
    const int xcd = flat & 7;
    const int j = flat >> 3;
    const int n_idx = xcd * 16 + (j & 15);
    const int rest = j >> 4;             // [0, 4*nz)
    const int o_idx = rest & 3;
    const int zi = rest >> 2;

    const unsigned short* Wtt = zi ? WttB : WttA;
    const unsigned short* prm = zi ? prmB : prmA;
    const float* bias = zi ? biasB : biasA;
    float* out = zi ? outB : outA;
    const int sig = zi ? sigB : sigA;

    const int t = threadIdx.x;
    const int w = t >> 6, l = t & 63;
    const int o0 = o_idx * 128, n0 = n_idx * 128;
    const int wn = w & 1, wo = w >> 1;
    const int l31 = l & 31, lh = l >> 5;
    // permute staging roles by block parity to spread VALU across SIMDs
    const int pw = (w + ((o_idx + n_idx) & 1) * 2) & 3;

    const half2v h2zero = {(_Float16)0.f, (_Float16)0.f};
    const half2v h2one  = {(_Float16)1.f, (_Float16)1.f};

    floatx16 acc[2][2];
    #pragma unroll
    for (int a = 0; a < 2; ++a)
        #pragma unroll
        for (int b = 0; b < 2; ++b)
            #pragma unroll
            for (int q = 0; q < 16; ++q) acc[a][b][q] = 0.f;

    for (int iter = 0; iter < KDIM / 32; ++iter) {
        const int i0 = iter * 4;
        if (pw < 2) {
            // ---- A role: n = pw*64 + l; 4 dims -> 32 fp16 ramp features
            const int n = pw * 64 + l;
            float4 xq = *(const float4*)&act[(size_t)(n0 + n) * DDIM + i0];
            float xs[4] = {xq.x, xq.y, xq.z, xq.w};
            #pragma unroll
            for (int jj = 0; jj < 4; ++jj) {
                const unsigned short* pb = prm + (size_t)(i0 + jj) * 16;
                uint4 iv = *(const uint4*)pb;        // 4x half2 inv
                uint4 ov = *(const uint4*)(pb + 8);  // 4x half2 ofs
                _Float16 xh = (_Float16)xs[jj];
                half2v x2 = {xh, xh};
                unsigned int invw[4] = {iv.x, iv.y, iv.z, iv.w};
                unsigned int ofsw[4] = {ov.x, ov.y, ov.z, ov.w};
                unsigned int fw[4];
                #pragma unroll
                for (int pp = 0; pp < 4; ++pp) {
                    half2v in2 = __builtin_bit_cast(half2v, invw[pp]);
                    half2v of2 = __builtin_bit_cast(half2v, ofsw[pp]);
                    half2v tt = x2 * in2 + of2;                 // v_pk_fma_f16
                    tt = __builtin_elementwise_max(tt, h2zero);
                    tt = __builtin_elementwise_min(tt, h2one);
                    fw[pp] = __builtin_bit_cast(unsigned int, tt);
                }
                uint4 pk = {fw[0], fw[1], fw[2], fw[3]};
                *(uint4*)&As[n * 40 + jj * 8] = pk;
            }
        } else {
            // ---- B role: u = (pw-2)*64 + l; copy Wtt tile (already fp16)
            const int u = (pw - 2) * 64 + l;
            #pragma unroll
            for (int jj = 0; jj < 4; ++jj) {
                uint4 bv = *(const uint4*)&Wtt[((size_t)(i0 + jj) * DDIM + o0 + u) * 8];
                *(uint4*)&Bs[jj * 1024 + u * 8] = bv;
            }
        }
        __syncthreads();

        // 32x32x16 f16: A[m=l&31][k=(l>>5)*8+j], B[k][n=l&31]
        #pragma unroll
        for (int kk = 0; kk < 2; ++kk) {           // two k-steps of 16
            half8 af[2], bfr[2];
            #pragma unroll
            for (int tn = 0; tn < 2; ++tn)
                af[tn] = *(const half8*)&As[(wn * 64 + tn * 32 + l31) * 40
                                            + kk * 16 + lh * 8];
            #pragma unroll
            for (int to = 0; to < 2; ++to)
                bfr[to] = *(const half8*)&Bs[(kk * 2 + lh) * 1024
                                             + (wo * 64 + to * 32 + l31) * 8];
            #pragma unroll
            for (int tn = 0; tn < 2; ++tn)
                #pragma unroll
                for (int to = 0; to < 2; ++to)
                    acc[tn][to] = __builtin_amdgcn_mfma_f32_32x32x16_f16(
                        af[tn], bfr[to], acc[tn][to], 0, 0, 0);
        }
        __syncthreads();
    }

    // epilogue: 32x32 C/D layout col=lane&31, row=(reg&3)+8*(reg>>2)+4*(lane>>5)
    #pragma unroll
    for (int tn = 0; tn < 2; ++tn) {
        #pragma unroll
        for (int to = 0; to < 2; ++to) {
            int col = o0 + wo * 64 + to * 32 + l31;
            float bv = bias[col];
            #pragma unroll
            for (int rr = 0; rr < 16; ++rr) {
                int row = n0 + wn * 64 + tn * 32 + (rr & 3) + 8 * (rr >> 2) + 4 * lh;
                float val = acc[tn][to][rr] + bv;
                if (sig) val = 1.f / (1.f + __expf(-val));
                out[(size_t)row * DDIM + col] = val;
            }
        }
    }
}

// ================= recurrence: chunked linear scan =================
#define RC_CH 64
#define RC_L  (TDIM / RC_CH)      // 32
#define NCHAIN (BDIM * DDIM)      // 4096

__global__ void rec_pass1(const float* __restrict__ z, const float* __restrict__ hb,
                          float* __restrict__ Aout, float* __restrict__ Bout) {
    int tid = blockIdx.x * blockDim.x + threadIdx.x;   // 0..262143
    int c = tid >> 12;
    int chain = tid & 4095;
    int b = chain >> 9, d = chain & 511;
    int base = ((b * TDIM) + c * RC_L) * DDIM + d;
    float ap = 1.f, h = 0.f;
    #pragma unroll 4
    for (int s = 0; s < RC_L; ++s) {
        float zz = z[base];
        float hh = hb[base];
        float a = 1.f - zz;
        h = fmaf(a, h, zz * hh);
        ap *= a;
        base += DDIM;
    }
    Aout[c * NCHAIN + chain] = ap;
    Bout[c * NCHAIN + chain] = h;
}

// fused pass2+pass3: compute chunk-start h by scanning summaries, then scan
__global__ void rec_pass23(float* __restrict__ z, const float* __restrict__ hb,
                           const float* __restrict__ A, const float* __restrict__ Bv) {
    int tid = blockIdx.x * blockDim.x + threadIdx.x;
    int c = tid >> 12;                 // uniform within a 256-thread block
    int chain = tid & 4095;
    float h = 0.f;                     // h0 = 0
    for (int cc = 0; cc < c; ++cc)
        h = fmaf(A[cc * NCHAIN + chain], h, Bv[cc * NCHAIN + chain]);
    int b = chain >> 9, d = chain & 511;
    int base = ((b * TDIM) + c * RC_L) * DDIM + d;
    #pragma unroll 4
    for (int s = 0; s < RC_L; ++s) {
        float zz = z[base];
        float hh = hb[base];
        h = fmaf(1.f - zz, h, zz * hh);
        z[base] = h;
        base += DDIM;
    }
}

// ================= maxabs norm: one wave per row =================
__global__ void norm_kernel(const float* __restrict__ h, float* __restrict__ out) {
    int wave = threadIdx.x >> 6;
    int lane = threadIdx.x & 63;
    int n = blockIdx.x * 4 + wave;
    const float4* row = (const float4*)&h[(size_t)n * DDIM];
    float4 v0 = row[lane];
    float4 v1 = row[lane + 64];
    float m = fmaxf(fmaxf(fabsf(v0.x), fabsf(v0.y)), fmaxf(fabsf(v0.z), fabsf(v0.w)));
    m = fmaxf(m, fmaxf(fmaxf(fabsf(v1.x), fabsf(v1.y)), fmaxf(fabsf(v1.z), fabsf(v1.w))));
    #pragma unroll
    for (int off = 32; off; off >>= 1) m = fmaxf(m, __shfl_xor(m, off, 64));
    float s = 1.0f / (m + EPSF);
    float4* orow = (float4*)&out[(size_t)n * DDIM];
    orow[lane]      = make_float4(v0.x * s, v0.y * s, v0.z * s, v0.w * s);
    orow[lane + 64] = make_float4(v1.x * s, v1.y * s, v1.z * s, v1.w * s);
}

// ================= orchestration =================
extern "C" void kernel_launch(void* const* d_in, const int* in_sizes, int n_in,
                              void* d_out, int out_size, void* d_ws, size_t ws_size,
                              hipStream_t stream) {
    const float* x   = (const float*)d_in[0];
    const float* pz0 = (const float*)d_in[1];
    const float* vz0 = (const float*)d_in[2];
    const float* ph0 = (const float*)d_in[3];
    const float* vh0 = (const float*)d_in[4];
    const float* pz1 = (const float*)d_in[5];
    const float* vz1 = (const float*)d_in[6];
    const float* ph1 = (const float*)d_in[7];
    const float* vh1 = (const float*)d_in[8];
    const float* po  = (const float*)d_in[9];
    const float* vo  = (const float*)d_in[10];

    float* out_r = (float*)d_out;
    float* h1_r  = out_r + (size_t)NTOK * DDIM;
    float* h2_r  = h1_r + (size_t)NTOK * DDIM;

    char* wp = (char*)d_ws;
    unsigned short* Wtt = (unsigned short*)wp; wp += (size_t)5 * KDIM * DDIM * 2;  // 20 MB
    unsigned short* prm = (unsigned short*)wp; wp += (size_t)5 * DDIM * 16 * 2;    // 80 KB
    float* bias = (float*)wp;  wp += 5 * DDIM * 4;
    float* Ab   = (float*)wp;  wp += RC_CH * NCHAIN * 4;
    float* Bb   = (float*)wp;  wp += RC_CH * NCHAIN * 4;

    const size_t WS = (size_t)KDIM * DDIM;   // Wtt slot stride
    const size_t PS = (size_t)DDIM * 16;     // prm slot stride

    // -------- all param prep up front (layers: 0=z0 1=h0 2=z1 3=h1 4=out)
    prep_prmh_kernel<<<5, 512, 0, stream>>>(pz0, ph0, pz1, ph1, po, prm, bias);
    prep_wtt_kernel<<<dim3((KDIM / 8) * DDIM / 256, 5), 256, 0, stream>>>(
        vz0, vh0, vz1, vh1, vo, Wtt);
    prep_bias_kernel<<<dim3(32, 5), 512, 0, stream>>>(vz0, vh0, vz1, vh1, vo, bias);

    auto recur = [&](float* zb, float* hb) {
        rec_pass1<<<(RC_CH * NCHAIN) / 256, 256, 0, stream>>>(zb, hb, Ab, Bb);
        rec_pass23<<<(RC_CH * NCHAIN) / 256, 256, 0, stream>>>(zb, hb, Ab, Bb);
    };

    // layer 1: z -> out_r (sigmoid), h_bar -> h1_r
    apl_gemm_mfma<<<1024, 256, 0, stream>>>(
        x, Wtt, Wtt + WS, prm, prm + PS, bias, bias + DDIM,
        out_r, h1_r, 1, 0);
    recur(out_r, h1_r);
    norm_kernel<<<NTOK / 4, 256, 0, stream>>>(out_r, h1_r);

    // layer 2
    apl_gemm_mfma<<<1024, 256, 0, stream>>>(
        h1_r, Wtt + 2 * WS, Wtt + 3 * WS, prm + 2 * PS, prm + 3 * PS,
        bias + 2 * DDIM, bias + 3 * DDIM, out_r, h2_r, 1, 0);
    recur(out_r, h2_r);
    norm_kernel<<<NTOK / 4, 256, 0, stream>>>(out_r, h2_r);

    // output APL (512 blocks, zi always 0)
    apl_gemm_mfma<<<512, 256, 0, stream>>>(
        h2_r, Wtt + 4 * WS, Wtt + 4 * WS, prm + 4 * PS, prm + 4 * PS,
        bias + 4 * DDIM, bias + 4 * DDIM, out_r, out_r, 0, 0);
}